// Round 8
// baseline (688.390 us; speedup 1.0000x reference)
//
#include <hip/hip_runtime.h>
#include <cmath>

#define BB 256
#define TT 512
#define NN 128
#define LN2F 0.6931471805599453f

typedef __bf16 bf16x8 __attribute__((ext_vector_type(8)));
typedef float floatx4 __attribute__((ext_vector_type(4)));

__device__ __forceinline__ float wave_max64(float v) {
    #pragma unroll
    for (int off = 32; off; off >>= 1) v = fmaxf(v, __shfl_xor(v, off));
    return v;
}
__device__ __forceinline__ float wave_sum64(float v) {
    #pragma unroll
    for (int off = 32; off; off >>= 1) v += __shfl_xor(v, off);
    return v;
}
// argmax over 128 values (lane l holds indices 2l, 2l+1); first-index tie-break.
__device__ __forceinline__ int wave_argmax128(float v0, float v1, int l) {
    float m = fmaxf(v0, v1);
    float wm = wave_max64(m);
    unsigned long long ball = __ballot(m == wm);
    int lane = __ffsll(ball) - 1;
    int idx = (v0 == wm) ? (2 * l) : (2 * l + 1);
    return __shfl(idx, lane);
}

__device__ __forceinline__ __bf16 to_bf16(float f) {   // RNE
    unsigned u = __float_as_uint(f);
    unsigned r = (u + 0x7FFFu + ((u >> 16) & 1u)) >> 16;
    union { unsigned short s; __bf16 b; } cv;
    cv.s = (unsigned short)r;
    return cv.b;
}

// Alpha layout: 16-float chunk g at word 20g (80 B: 16B-aligned, 8 disjoint
// 4-bank groups {0,20,8,28,16,4,24,12} -> conflict-free).
__device__ __forceinline__ int pidx(int i) { return 20 * (i >> 4) + (i & 15); }

// Forward: 1024 threads/batch, 16 waves, one barrier/step.
//   ALL 16 waves: tracked Viterbi, col=(l&7)+8w, i-chunk g=l>>3 (16 i's).
//     Exact fp32 max-plus; (val,idx) combine via 3-stage xor butterfly.
//   Waves 8-15 additionally: log-norm via MFMA (r7 scheme: wave 8+g owns cols
//     16g..16g+15, E=exp(trans) bf16 B-frags, s bf16 in LDS dbl-buffered).
// Backtrace: u8 bp in LDS, 3-phase parallel (maps + compose + re-trace).
__global__ __launch_bounds__(1024, 4) void fwd_kernel(
        const float* __restrict__ em, const int* __restrict__ mask,
        const float* __restrict__ trans, float* __restrict__ outp,
        float* __restrict__ lognorm) {
    const int b = blockIdx.x;
    const int tid = threadIdx.x;
    const int w = tid >> 6;
    const int l = tid & 63;
    const int j = (l & 7) + 8 * w;     // Viterbi column (0..127, unique/thread-group)
    const int g = l >> 3;              // i-chunk (16 i's)
    const int i0 = 16 * g;
    const bool isS = (w >= 8);
    const int js = (l & 15) + 16 * (w & 7);   // log-norm column (S waves)
    const int qs = l >> 4;

    __shared__ __align__(16) float apad[2][160];       // viterbi alpha ping-pong
    __shared__ __align__(16) __bf16 sbf[2][NN];        // log-norm s (bf16) dbl-buf
    __shared__ unsigned char bp_lds[TT * NN];          // 64 KB backpointers
    __shared__ unsigned char tags_lds[TT];
    __shared__ unsigned char map_lds[8 * NN];          // backtrace chunk maps
    __shared__ int entry_sh[8];
    __shared__ int msk[TT];
    __shared__ float piv[2];
    __shared__ float sfin[NN];
    __shared__ int misc[2];                            // [0]=lastTag [1]=kacc

    if (tid < TT) msk[tid] = mask[b * TT + tid];

    const float* emb = em + (size_t)b * TT * NN;

    float C[16];        // all waves: trans[i0+r][j] for Viterbi
    {
        const float* tc = trans + (size_t)i0 * NN + j;
        #pragma unroll
        for (int r = 0; r < 16; ++r) C[r] = tc[(size_t)r * NN];
    }
    bf16x8 Bf[4];       // S waves: B-fragments of exp(trans)
    if (isS) {
        #pragma unroll
        for (int kc = 0; kc < 4; ++kc) {
            #pragma unroll
            for (int jj = 0; jj < 8; ++jj) {
                int row = kc * 32 + qs * 8 + jj;
                Bf[kc][jj] = to_bf16(__expf(trans[(size_t)row * NN + js]));
            }
        }
    }

    float st = 0.f;     // viterbi alpha for col j (valid on writer lanes l<8)
    float ss = 0.f;     // log-norm s for col js (S waves)
    int kacc = 0;
    {
        float a0 = emb[j];
        st = a0;
        if (l < 8) apad[0][pidx(j)] = a0;
        if (isS) {
            ss = __expf(emb[js]);
            if (l < 16) sbf[0][js] = to_bf16(ss);
            if (w == 8 && l == 0) piv[0] = ss;
        }
    }
    float e_next = emb[NN + j];
    float es_next = isS ? emb[NN + js] : 0.f;
    __syncthreads();

    for (int t = 1; t < TT; ++t) {
        const float e_cur = e_next;
        const float es_cur = es_next;
        if (t + 1 < TT) {
            e_next = emb[(size_t)(t + 1) * NN + j];
            if (isS) es_next = emb[(size_t)(t + 1) * NN + js];
        }
        const int m = msk[t];
        const int p = (t - 1) & 1, qb = t & 1;

        // ---- Viterbi (all 16 waves), 16 i's per thread ----
        {
            const float4* ap = (const float4*)(apad[p] + 20 * g);
            float m0 = -INFINITY, m1 = -INFINITY, m2 = -INFINITY, m3 = -INFINITY;
            int u0 = 0, u1 = 0, u2 = 0, u3 = 0;
            #pragma unroll
            for (int u = 0; u < 4; ++u) {
                float4 v = ap[u];
                float c0 = v.x + C[4*u+0]; u0 = (c0 > m0) ? u : u0; m0 = fmaxf(m0, c0);
                float c1 = v.y + C[4*u+1]; u1 = (c1 > m1) ? u : u1; m1 = fmaxf(m1, c1);
                float c2 = v.z + C[4*u+2]; u2 = (c2 > m2) ? u : u2; m2 = fmaxf(m2, c2);
                float c3 = v.w + C[4*u+3]; u3 = (c3 > m3) ? u : u3; m3 = fmaxf(m3, c3);
            }
            float bv = m0; int bx = i0 + 4 * u0;
            { int id = i0 + 4*u1 + 1; if (m1 > bv || (m1 == bv && id < bx)) { bv = m1; bx = id; } }
            { int id = i0 + 4*u2 + 2; if (m2 > bv || (m2 == bv && id < bx)) { bv = m2; bx = id; } }
            { int id = i0 + 4*u3 + 3; if (m3 > bv || (m3 == bv && id < bx)) { bv = m3; bx = id; } }
            #pragma unroll
            for (int off = 8; off <= 32; off <<= 1) {
                float ov = __shfl_xor(bv, off);
                int oi = __shfl_xor(bx, off);
                if (ov > bv || (ov == bv && oi < bx)) { bv = ov; bx = oi; }
            }
            if (l < 8) {
                float an; int bp;
                if (m) { an = bv + e_cur; bp = bx; }   // plain add = reference-exact
                else   { an = st;         bp = j;  }   // identity bp when masked
                st = an;
                apad[qb][pidx(j)] = an;
                bp_lds[t * NN + j] = (unsigned char)bp;
            }
        }

        // ---- log-norm via MFMA (waves 8-15) ----
        if (isS) {
            if (m) {
                const __bf16* sp = sbf[p];
                floatx4 acc = {0.f, 0.f, 0.f, 0.f};
                #pragma unroll
                for (int kc = 0; kc < 4; ++kc) {
                    bf16x8 a = *(const bf16x8*)(sp + kc * 32 + qs * 8);
                    acc = __builtin_amdgcn_mfma_f32_16x16x32_bf16(a, Bf[kc], acc, 0, 0, 0);
                }
                float dot = acc[0];                    // rows identical -> all regs equal
                const float pv = piv[p];
                const int k = (int)(__float_as_uint(pv) >> 23) - 127;
                const float scale = __uint_as_float((unsigned)(127 - k) << 23);  // 2^-k
                ss = dot * scale * __expf(es_cur);
                if (w == 8 && l == 0) kacc += k;
            }
            if (l < 16) sbf[qb][js] = to_bf16(ss);
            if (w == 8 && l == 0) piv[qb] = ss;
        }
        __syncthreads();
    }

    // ---- epilogue ----
    if (isS && l < 16) sfin[js] = ss;
    if (w == 8 && l == 0) misc[1] = kacc;
    if (w == 0) {   // last-tag argmax over final alpha (buf 1: TT-1 odd)
        float a0 = apad[1][pidx(2 * l)], a1 = apad[1][pidx(2 * l + 1)];
        int tg = wave_argmax128(a0, a1, l);
        if (l == 0) { misc[0] = tg; tags_lds[TT - 1] = (unsigned char)tg; }
    }
    __syncthreads();

    // Phase 1 (waves 0-7): speculative 64-step chunk maps for all 128 entries.
    const int lo = 64 * (w & 7) + 1;
    const int hi = ((w & 7) == 7) ? (TT - 1) : (64 * (w & 7) + 64);
    if (w < 8) {
        int tA = 2 * l, tB = 2 * l + 1;
        for (int t = hi; t >= lo; --t) {
            tA = bp_lds[t * NN + tA];
            tB = bp_lds[t * NN + tB];
        }
        map_lds[(w & 7) * NN + 2 * l]     = (unsigned char)tA;
        map_lds[(w & 7) * NN + 2 * l + 1] = (unsigned char)tB;
    } else if (w == 8) {   // log-norm final reduction (off critical path)
        float v = sfin[2 * l] + sfin[2 * l + 1];
        v = wave_sum64(v);
        if (l == 0) lognorm[b] = __logf(v) + (float)misc[1] * LN2F;
    }
    __syncthreads();
    // Phase 2: compose chunk maps -> true entry tag per chunk.
    if (tid == 0) {
        int e = misc[0];
        entry_sh[7] = e;
        for (int c = 7; c >= 1; --c) { e = map_lds[c * NN + e]; entry_sh[c - 1] = e; }
    }
    __syncthreads();
    // Phase 3: re-trace each chunk from its true entry.
    if (w < 8 && l == 0) {
        int tg = entry_sh[w];
        for (int t = hi; t >= lo; --t) {
            tg = bp_lds[t * NN + tg];
            tags_lds[t - 1] = (unsigned char)tg;
        }
    }
    __syncthreads();
    if (tid < TT) outp[(size_t)b * TT + tid] = (float)tags_lds[tid];
}

// Gold-path score + final LL. One block (128 threads) per batch.
__global__ __launch_bounds__(128, 1) void score_kernel(
        const float* __restrict__ em, const int* __restrict__ tags,
        const int* __restrict__ mask, const float* __restrict__ trans,
        const float* __restrict__ lognorm, float* __restrict__ out_ll) {
    const int b = blockIdx.x;
    const int tid = threadIdx.x;
    float acc = 0.f;
    for (int t = tid; t < TT; t += 128) {
        int tg = tags[b * TT + t];
        float mf = (float)mask[b * TT + t];
        acc += em[((size_t)b * TT + t) * NN + tg] * mf;
        if (t >= 1) {
            int tp = tags[b * TT + t - 1];
            acc += trans[tp * NN + tg] * mf;
        }
    }
    acc = wave_sum64(acc);
    __shared__ float rs[2];
    if ((tid & 63) == 0) rs[tid >> 6] = acc;
    __syncthreads();
    if (tid == 0) out_ll[b] = (rs[0] + rs[1]) - lognorm[b];
}

__global__ void copy_trans_kernel(const float* __restrict__ trans,
                                  float* __restrict__ dst) {
    int i = blockIdx.x * 256 + threadIdx.x;
    if (i < NN * NN) dst[i] = trans[i];
}

extern "C" void kernel_launch(void* const* d_in, const int* in_sizes, int n_in,
                              void* d_out, int out_size, void* d_ws, size_t ws_size,
                              hipStream_t stream) {
    const float* em = (const float*)d_in[0];
    const int* tags = (const int*)d_in[1];
    const int* mask = (const int*)d_in[2];
    const float* trans = (const float*)d_in[3];

    float* out = (float*)d_out;
    float* out_ll = out;
    float* out_trans = out + BB;
    float* out_pred = out + BB + NN * NN;

    float* lognorm = (float*)d_ws;   // [256]

    hipLaunchKernelGGL(fwd_kernel, dim3(BB), dim3(1024), 0, stream,
                       em, mask, trans, out_pred, lognorm);
    hipLaunchKernelGGL(copy_trans_kernel, dim3(64), dim3(256), 0, stream,
                       trans, out_trans);
    hipLaunchKernelGGL(score_kernel, dim3(BB), dim3(128), 0, stream,
                       em, tags, mask, trans, lognorm, out_ll);
}

// Round 9
// 541.492 us; speedup vs baseline: 1.2713x; 1.2713x over previous
//
#include <hip/hip_runtime.h>
#include <cmath>

#define BB 256
#define TT 512
#define NN 128
#define LN2F 0.6931471805599453f

typedef __bf16 bf16x8 __attribute__((ext_vector_type(8)));
typedef float floatx4 __attribute__((ext_vector_type(4)));

__device__ __forceinline__ float wave_max64(float v) {
    #pragma unroll
    for (int off = 32; off; off >>= 1) v = fmaxf(v, __shfl_xor(v, off));
    return v;
}
__device__ __forceinline__ float wave_sum64(float v) {
    #pragma unroll
    for (int off = 32; off; off >>= 1) v += __shfl_xor(v, off);
    return v;
}
// argmax over 128 values (lane l holds indices 2l, 2l+1); first-index tie-break.
__device__ __forceinline__ int wave_argmax128(float v0, float v1, int l) {
    float m = fmaxf(v0, v1);
    float wm = wave_max64(m);
    unsigned long long ball = __ballot(m == wm);
    int lane = __ffsll(ball) - 1;
    int idx = (v0 == wm) ? (2 * l) : (2 * l + 1);
    return __shfl(idx, lane);
}

__device__ __forceinline__ __bf16 to_bf16(float f) {   // RNE
    unsigned u = __float_as_uint(f);
    unsigned r = (u + 0x7FFFu + ((u >> 16) & 1u)) >> 16;
    union { unsigned short s; __bf16 b; } cv;
    cv.s = (unsigned short)r;
    return cv.b;
}

// Padded state layout: 32-float chunk c starts at word 36c (bank offset 4c).
__device__ __forceinline__ int padidx(int i) { return 36 * (i >> 5) + (i & 31); }

// Forward. grid = 2*BB, 512-thread blocks (8 waves), 2 blocks/CU.
//   Blocks 0..BB-1   : Viterbi for batch b=bi (tracked argmax, u8 bp in LDS,
//                      3-phase parallel backtrace). col j=(l&15)+16w, chunk q=l>>4.
//   Blocks BB..2BB-1 : log-norm for batch b=bi-BB via MFMA (wave w owns cols
//                      16w..16w+15; E=exp(trans) bf16 B-frags; s bf16 dbl-buf).
// Pairing b <-> b+BB puts one V + one S block per CU under linear or
// XCD-round-robin dispatch -> light S chain fills heavy V chain's stalls.
__global__ __launch_bounds__(512, 4) void fwd_kernel(
        const float* __restrict__ em, const int* __restrict__ mask,
        const float* __restrict__ trans, float* __restrict__ outp,
        float* __restrict__ lognorm) {
    const int bi = blockIdx.x;
    const bool isV = bi < BB;
    const int b = isV ? bi : bi - BB;
    const int tid = threadIdx.x;
    const int w = tid >> 6;
    const int l = tid & 63;
    const int j = (l & 15) + 16 * w;   // column (V: unique per (w,l&15); S: same)
    const int q = l >> 4;              // V: i-chunk of 32; S: quad
    const int i0 = 32 * q;

    __shared__ __align__(16) float stA[144], stB[144];  // V alpha ping-pong
    __shared__ __align__(16) __bf16 sbf[2][NN];         // S state (bf16) dbl-buf
    __shared__ unsigned char bp_lds[TT * NN];           // V: 64 KB backpointers
    __shared__ unsigned char tags_lds[TT];
    __shared__ unsigned char map_lds[8 * NN];
    __shared__ int entry_sh[8];
    __shared__ int msk[TT];
    __shared__ float piv[2];
    __shared__ float sfin[NN];
    __shared__ int misc[2];                             // [0]=lastTag [1]=kacc

    msk[tid] = mask[b * TT + tid];

    const float* emb = em + (size_t)b * TT * NN;

    if (isV) {
        float C[32];
        {
            const float* tc = trans + (size_t)i0 * NN + j;
            #pragma unroll
            for (int r = 0; r < 32; ++r) C[r] = tc[(size_t)r * NN];
        }
        float st = 0.f;
        {
            float a0 = emb[j];
            st = a0;
            if (l < 16) stA[padidx(j)] = a0;
        }
        float e_next = emb[NN + j];
        __syncthreads();

        const float4* apA = (const float4*)(stA + 36 * q);
        const float4* apB = (const float4*)(stB + 36 * q);

        auto VSTEP = [&](int t, const float4* ap, float* dst) {
            const float e_cur = e_next;
            if (t + 1 < TT) e_next = emb[(size_t)(t + 1) * NN + j];
            const int m = msk[t];
            float m0 = -INFINITY, m1 = -INFINITY, m2 = -INFINITY, m3 = -INFINITY;
            int u0 = 0, u1 = 0, u2 = 0, u3 = 0;
            #pragma unroll
            for (int u = 0; u < 8; ++u) {
                float4 v = ap[u];
                float c0 = v.x + C[4*u+0]; u0 = (c0 > m0) ? u : u0; m0 = fmaxf(m0, c0);
                float c1 = v.y + C[4*u+1]; u1 = (c1 > m1) ? u : u1; m1 = fmaxf(m1, c1);
                float c2 = v.z + C[4*u+2]; u2 = (c2 > m2) ? u : u2; m2 = fmaxf(m2, c2);
                float c3 = v.w + C[4*u+3]; u3 = (c3 > m3) ? u : u3; m3 = fmaxf(m3, c3);
            }
            float bv = m0; int bx = i0 + 4 * u0;
            { int id = i0 + 4*u1 + 1; if (m1 > bv || (m1 == bv && id < bx)) { bv = m1; bx = id; } }
            { int id = i0 + 4*u2 + 2; if (m2 > bv || (m2 == bv && id < bx)) { bv = m2; bx = id; } }
            { int id = i0 + 4*u3 + 3; if (m3 > bv || (m3 == bv && id < bx)) { bv = m3; bx = id; } }
            #pragma unroll
            for (int off = 16; off <= 32; off <<= 1) {
                float ov = __shfl_xor(bv, off);
                int oi = __shfl_xor(bx, off);
                if (ov > bv || (ov == bv && oi < bx)) { bv = ov; bx = oi; }
            }
            if (l < 16) {
                float an; int bp;
                if (m) { an = bv + e_cur; bp = bx; }   // plain add = reference-exact
                else   { an = st;         bp = j;  }   // identity bp when masked
                st = an;
                dst[padidx(j)] = an;
                bp_lds[t * NN + j] = (unsigned char)bp;
            }
            __syncthreads();
        };

        for (int t = 1; t < TT - 1; t += 2) {
            VSTEP(t, apA, stB);
            VSTEP(t + 1, apB, stA);
        }
        VSTEP(TT - 1, apA, stB);   // final alpha in stB

        if (w == 0) {   // last-tag argmax (exact, first-index ties)
            float a0 = stB[padidx(2 * l)], a1 = stB[padidx(2 * l + 1)];
            int tg = wave_argmax128(a0, a1, l);
            if (l == 0) { misc[0] = tg; tags_lds[TT - 1] = (unsigned char)tg; }
        }
        __syncthreads();
        // Phase 1: each wave maps all 128 entry tags through its 64-step chunk.
        const int lo = 64 * w + 1;
        const int hi = (w == 7) ? (TT - 1) : (64 * w + 64);
        {
            int tA = 2 * l, tB = 2 * l + 1;
            for (int t = hi; t >= lo; --t) {
                tA = bp_lds[t * NN + tA];
                tB = bp_lds[t * NN + tB];
            }
            map_lds[w * NN + 2 * l]     = (unsigned char)tA;
            map_lds[w * NN + 2 * l + 1] = (unsigned char)tB;
        }
        __syncthreads();
        // Phase 2: compose chunk maps -> true entry tag per chunk.
        if (tid == 0) {
            int e = misc[0];
            entry_sh[7] = e;
            for (int c = 7; c >= 1; --c) { e = map_lds[c * NN + e]; entry_sh[c - 1] = e; }
        }
        __syncthreads();
        // Phase 3: re-trace each chunk from its true entry.
        if (l == 0) {
            int tg = entry_sh[w];
            for (int t = hi; t >= lo; --t) {
                tg = bp_lds[t * NN + tg];
                tags_lds[t - 1] = (unsigned char)tg;
            }
        }
        __syncthreads();
        outp[(size_t)b * TT + tid] = (float)tags_lds[tid];
    } else {
        bf16x8 Bf[4];
        #pragma unroll
        for (int kc = 0; kc < 4; ++kc) {
            #pragma unroll
            for (int jj = 0; jj < 8; ++jj) {
                int row = kc * 32 + q * 8 + jj;
                Bf[kc][jj] = to_bf16(__expf(trans[(size_t)row * NN + j]));
            }
        }
        float ss = __expf(emb[j]);
        int kacc = 0;
        if (l < 16) sbf[0][j] = to_bf16(ss);
        if (tid == 0) piv[0] = ss;
        float e_next = emb[NN + j];
        __syncthreads();

        for (int t = 1; t < TT; ++t) {
            const float e_cur = e_next;
            if (t + 1 < TT) e_next = emb[(size_t)(t + 1) * NN + j];
            const int m = msk[t];
            const int p = (t - 1) & 1, qb = t & 1;
            if (m) {
                const __bf16* sp = sbf[p];
                floatx4 acc = {0.f, 0.f, 0.f, 0.f};
                #pragma unroll
                for (int kc = 0; kc < 4; ++kc) {
                    bf16x8 a = *(const bf16x8*)(sp + kc * 32 + q * 8);
                    acc = __builtin_amdgcn_mfma_f32_16x16x32_bf16(a, Bf[kc], acc, 0, 0, 0);
                }
                float dot = acc[0];                    // rows identical -> regs equal
                const float pv = piv[p];
                const int k = (int)(__float_as_uint(pv) >> 23) - 127;
                const float scale = __uint_as_float((unsigned)(127 - k) << 23);  // 2^-k
                ss = dot * scale * __expf(e_cur);
                if (tid == 0) kacc += k;
            }
            if (l < 16) sbf[qb][j] = to_bf16(ss);
            if (tid == 0) piv[qb] = ss;
            __syncthreads();
        }

        if (l < 16) sfin[j] = ss;
        if (tid == 0) misc[1] = kacc;
        __syncthreads();
        if (w == 0) {
            float v = sfin[2 * l] + sfin[2 * l + 1];
            v = wave_sum64(v);
            if (l == 0) lognorm[b] = __logf(v) + (float)misc[1] * LN2F;
        }
    }
}

// Gold-path score + final LL. One block (128 threads) per batch.
__global__ __launch_bounds__(128, 1) void score_kernel(
        const float* __restrict__ em, const int* __restrict__ tags,
        const int* __restrict__ mask, const float* __restrict__ trans,
        const float* __restrict__ lognorm, float* __restrict__ out_ll) {
    const int b = blockIdx.x;
    const int tid = threadIdx.x;
    float acc = 0.f;
    for (int t = tid; t < TT; t += 128) {
        int tg = tags[b * TT + t];
        float mf = (float)mask[b * TT + t];
        acc += em[((size_t)b * TT + t) * NN + tg] * mf;
        if (t >= 1) {
            int tp = tags[b * TT + t - 1];
            acc += trans[tp * NN + tg] * mf;
        }
    }
    acc = wave_sum64(acc);
    __shared__ float rs[2];
    if ((tid & 63) == 0) rs[tid >> 6] = acc;
    __syncthreads();
    if (tid == 0) out_ll[b] = (rs[0] + rs[1]) - lognorm[b];
}

__global__ void copy_trans_kernel(const float* __restrict__ trans,
                                  float* __restrict__ dst) {
    int i = blockIdx.x * 256 + threadIdx.x;
    if (i < NN * NN) dst[i] = trans[i];
}

extern "C" void kernel_launch(void* const* d_in, const int* in_sizes, int n_in,
                              void* d_out, int out_size, void* d_ws, size_t ws_size,
                              hipStream_t stream) {
    const float* em = (const float*)d_in[0];
    const int* tags = (const int*)d_in[1];
    const int* mask = (const int*)d_in[2];
    const float* trans = (const float*)d_in[3];

    float* out = (float*)d_out;
    float* out_ll = out;
    float* out_trans = out + BB;
    float* out_pred = out + BB + NN * NN;

    float* lognorm = (float*)d_ws;   // [256]

    hipLaunchKernelGGL(fwd_kernel, dim3(2 * BB), dim3(512), 0, stream,
                       em, mask, trans, out_pred, lognorm);
    hipLaunchKernelGGL(copy_trans_kernel, dim3(64), dim3(256), 0, stream,
                       trans, out_trans);
    hipLaunchKernelGGL(score_kernel, dim3(BB), dim3(128), 0, stream,
                       em, tags, mask, trans, lognorm, out_ll);
}